// Round 2
// baseline (1195.848 us; speedup 1.0000x reference)
//
#include <hip/hip_runtime.h>
#include <cstdint>
#include <cstddef>

#define N_NODES 50000
#define N_EDGES 800000
#define D 128
#define DE 16
#define NBLK 196   // ceil(50000/256)

// ---------------------------------------------------------------------------
// CSR build (dst-sorted, graph j=2, shared by both layers)
// ---------------------------------------------------------------------------
__global__ void csr_hist(const int* __restrict__ dst, int* __restrict__ count){
  int e = blockIdx.x*256 + threadIdx.x;
  if (e < N_EDGES) atomicAdd(&count[dst[e]], 1);
}

__global__ __launch_bounds__(256) void csr_blocksum(const int* __restrict__ count,
                                                    int* __restrict__ bsum){
  __shared__ int red[4];
  int i = blockIdx.x*256 + threadIdx.x;
  int v = (i < N_NODES) ? count[i] : 0;
  #pragma unroll
  for (int off=32; off; off>>=1) v += __shfl_down(v, off);
  if ((threadIdx.x & 63) == 0) red[threadIdx.x>>6] = v;
  __syncthreads();
  if (threadIdx.x == 0) bsum[blockIdx.x] = red[0]+red[1]+red[2]+red[3];
}

__global__ __launch_bounds__(256) void csr_scan_bsum(const int* __restrict__ bsum,
                                                     int* __restrict__ boff){
  __shared__ int s[256];
  int t = threadIdx.x;
  int v = (t < NBLK) ? bsum[t] : 0;
  s[t] = v; __syncthreads();
  for (int off=1; off<256; off<<=1){
    int u = (t >= off) ? s[t-off] : 0;
    __syncthreads(); s[t] += u; __syncthreads();
  }
  if (t < NBLK) boff[t] = s[t] - v;   // exclusive
}

__global__ __launch_bounds__(256) void csr_downsweep(const int* __restrict__ count,
    const int* __restrict__ boff, int* __restrict__ row_start, int* __restrict__ cursor){
  __shared__ int s[256];
  int t = threadIdx.x;
  int i = blockIdx.x*256 + t;
  int v = (i < N_NODES) ? count[i] : 0;
  s[t] = v; __syncthreads();
  for (int off=1; off<256; off<<=1){
    int u = (t >= off) ? s[t-off] : 0;
    __syncthreads(); s[t] += u; __syncthreads();
  }
  int excl = boff[blockIdx.x] + s[t] - v;
  if (i <= N_NODES) row_start[i] = excl;
  if (i <  N_NODES) cursor[i]   = excl;
}

__global__ void csr_scatter(const int* __restrict__ src, const int* __restrict__ dst,
                            int* __restrict__ cursor, int* __restrict__ perm,
                            int* __restrict__ src_perm){
  int e = blockIdx.x*256 + threadIdx.x;
  if (e >= N_EDGES) return;
  int d = dst[e];
  int pos = atomicAdd(&cursor[d], 1);
  perm[pos] = e;
  src_perm[pos] = src[e];
}

// ---------------------------------------------------------------------------
// LSTM: P[t][r] = Wih[r] . x[t] + (bih[r]+bhh[r])   (wide, parallel)
// ---------------------------------------------------------------------------
__global__ __launch_bounds__(512) void lstm_pre(const float* __restrict__ Wih,
     const float* __restrict__ bih, const float* __restrict__ bhh,
     const float* __restrict__ xin, float* __restrict__ P){
  __shared__ float xs[128];
  int i = blockIdx.x >> 7, t = blockIdx.x & 127;
  const float* x = xin + (size_t)i*16384;
  if (threadIdx.x < 128) xs[threadIdx.x] = x[t*128 + threadIdx.x];
  __syncthreads();
  int r = threadIdx.x;
  const float4* wr = (const float4*)(Wih + (size_t)(i*512 + r)*128);
  const float4* x4 = (const float4*)xs;
  float acc = bih[i*512+r] + bhh[i*512+r];
  #pragma unroll
  for (int k=0;k<32;k++){
    float4 w = wr[k]; float4 xv = x4[k];
    acc += w.x*xv.x + w.y*xv.y + w.z*xv.z + w.w*xv.w;
  }
  P[(size_t)(i*128+t)*512 + r] = acc;
}

// Recurrent scan. 256 threads, 2 rows/thread (r, r+256). h broadcast via
// v_readlane from registers (VALU pipe) instead of LDS reads.
// rows: [0,128)=i  [128,256)=f  [256,384)=g(tanh)  [384,512)=o
// thread tid<128:  acc0=i[tid],      acc1=g[tid]
// thread tid>=128: acc0=f[tid-128],  acc1=o[tid-128]
__global__ __launch_bounds__(256, 1) void lstm_scan(const float* __restrict__ Whh,
     const float* __restrict__ P, float* __restrict__ xout){
  __shared__ float hs[128];
  __shared__ float gs[512];
  const int i = blockIdx.x, tid = threadIdx.x;
  const int lane = tid & 63;
  float4 wreg0[32], wreg1[32];
  {
    const float4* wr0 = (const float4*)(Whh + (size_t)(i*512 + tid      )*128);
    const float4* wr1 = (const float4*)(Whh + (size_t)(i*512 + tid + 256)*128);
    #pragma unroll
    for (int k=0;k<32;k++){ wreg0[k] = wr0[k]; wreg1[k] = wr1[k]; }
  }
  float c = 0.f;
  float h0 = 0.f, h1 = 0.f;          // h[lane], h[64+lane]
  const float* Pi = P + (size_t)i*128*512;
  for (int t=0;t<128;t++){
    float acc0 = Pi[t*512 + tid];
    float acc1 = Pi[t*512 + tid + 256];
    int ih0 = __float_as_int(h0), ih1 = __float_as_int(h1);
    #pragma unroll
    for (int k=0;k<16;k++){
      float b0 = __int_as_float(__builtin_amdgcn_readlane(ih0, 4*k+0));
      float b1 = __int_as_float(__builtin_amdgcn_readlane(ih0, 4*k+1));
      float b2 = __int_as_float(__builtin_amdgcn_readlane(ih0, 4*k+2));
      float b3 = __int_as_float(__builtin_amdgcn_readlane(ih0, 4*k+3));
      float4 w0 = wreg0[k], w1 = wreg1[k];
      acc0 += w0.x*b0 + w0.y*b1 + w0.z*b2 + w0.w*b3;
      acc1 += w1.x*b0 + w1.y*b1 + w1.z*b2 + w1.w*b3;
    }
    #pragma unroll
    for (int k=16;k<32;k++){
      int kk = 4*k - 64;
      float b0 = __int_as_float(__builtin_amdgcn_readlane(ih1, kk+0));
      float b1 = __int_as_float(__builtin_amdgcn_readlane(ih1, kk+1));
      float b2 = __int_as_float(__builtin_amdgcn_readlane(ih1, kk+2));
      float b3 = __int_as_float(__builtin_amdgcn_readlane(ih1, kk+3));
      float4 w0 = wreg0[k], w1 = wreg1[k];
      acc0 += w0.x*b0 + w0.y*b1 + w0.z*b2 + w0.w*b3;
      acc1 += w1.x*b0 + w1.y*b1 + w1.z*b2 + w1.w*b3;
    }
    // nonlinearity
    float g0 = __builtin_amdgcn_rcpf(1.f + __expf(-acc0));   // sigmoid(acc0)
    float g1;
    if (tid < 128){                                          // g gate: tanh
      float xc = fminf(fmaxf(acc1, -15.f), 15.f);
      float e2 = __expf(2.f*xc);
      g1 = (e2 - 1.f) * __builtin_amdgcn_rcpf(e2 + 1.f);
    } else {                                                 // o gate: sigmoid
      g1 = __builtin_amdgcn_rcpf(1.f + __expf(-acc1));
    }
    gs[tid]     = g0;   // i (tid<128) / f (tid>=128 -> index 128+(tid-128))
    gs[256+tid] = g1;   // g (tid<128) / o (tid>=128 -> index 384+(tid-128))
    __syncthreads();
    if (tid < 128){
      c = gs[128+tid]*c + gs[tid]*gs[256+tid];
      float xc = fminf(fmaxf(c, -15.f), 15.f);
      float e2 = __expf(2.f*xc);
      float th = (e2 - 1.f) * __builtin_amdgcn_rcpf(e2 + 1.f);
      float h = gs[384+tid]*th;
      hs[tid] = h;
      xout[(size_t)(i*128+t)*128 + tid] = h;
    }
    __syncthreads();
    h0 = hs[lane];
    h1 = hs[64+lane];
  }
}

// ---------------------------------------------------------------------------
// GAT stage A: ft = f @ W (50000x128 @ 128x128, fp32) + s_src = f @ a_src
// ---------------------------------------------------------------------------
__global__ __launch_bounds__(256) void gat_transform(const float* __restrict__ f,
    const float* __restrict__ W, const float* __restrict__ aw,
    float* __restrict__ ft, float* __restrict__ s_src){
  __shared__ float Ws[64*128];
  __shared__ float fs[128*36];
  int n0 = blockIdx.x * 32;
  {
    int n = threadIdx.x >> 3, kq = threadIdx.x & 7;
    int gn = n0 + n;
    #pragma unroll
    for (int p=0;p<4;p++){
      int k = kq*16 + p*4;
      float4 v = make_float4(0.f,0.f,0.f,0.f);
      if (gn < N_NODES) v = *(const float4*)(f + (size_t)gn*128 + k);
      fs[(k+0)*36+n] = v.x; fs[(k+1)*36+n] = v.y;
      fs[(k+2)*36+n] = v.z; fs[(k+3)*36+n] = v.w;
    }
  }
  int jg = threadIdx.x & 31, ng = threadIdx.x >> 5;
  float4 a0=make_float4(0,0,0,0), a1=a0, a2=a0, a3=a0;
  for (int kk=0; kk<128; kk+=64){
    __syncthreads();
    {
      const float4* W4 = (const float4*)(W + (size_t)kk*128);
      float4* Ws4w = (float4*)Ws;
      for (int idx = threadIdx.x; idx < 2048; idx += 256) Ws4w[idx] = W4[idx];
    }
    __syncthreads();
    const float4* Ws4 = (const float4*)Ws;
    #pragma unroll 4
    for (int k2=0;k2<64;k2++){
      float4 wv = Ws4[k2*32 + jg];
      float4 fv = *(const float4*)&fs[(kk+k2)*36 + (ng<<2)];
      a0.x += fv.x*wv.x; a0.y += fv.x*wv.y; a0.z += fv.x*wv.z; a0.w += fv.x*wv.w;
      a1.x += fv.y*wv.x; a1.y += fv.y*wv.y; a1.z += fv.y*wv.z; a1.w += fv.y*wv.w;
      a2.x += fv.z*wv.x; a2.y += fv.z*wv.y; a2.z += fv.z*wv.z; a2.w += fv.z*wv.w;
      a3.x += fv.w*wv.x; a3.y += fv.w*wv.y; a3.z += fv.w*wv.z; a3.w += fv.w*wv.w;
    }
  }
  int nb = n0 + (ng<<2);
  if (nb+0 < N_NODES) *(float4*)(ft + (size_t)(nb+0)*128 + (jg<<2)) = a0;
  if (nb+1 < N_NODES) *(float4*)(ft + (size_t)(nb+1)*128 + (jg<<2)) = a1;
  if (nb+2 < N_NODES) *(float4*)(ft + (size_t)(nb+2)*128 + (jg<<2)) = a2;
  if (nb+3 < N_NODES) *(float4*)(ft + (size_t)(nb+3)*128 + (jg<<2)) = a3;
  if (threadIdx.x < 32){
    int gn = n0 + threadIdx.x;
    if (gn < N_NODES){
      float s = 0.f;
      for (int k=0;k<128;k++) s += fs[k*36 + threadIdx.x] * aw[k];
      s_src[gn] = s;
    }
  }
}

// ---------------------------------------------------------------------------
// GAT stage B: score[p] = s_src[src_perm[p]] + ef[perm[p]] . a_edge
// ---------------------------------------------------------------------------
__global__ __launch_bounds__(256) void gat_edge_score(const int* __restrict__ perm,
    const int* __restrict__ src_perm, const float* __restrict__ s_src,
    const float* __restrict__ ef, const float* __restrict__ aw,
    float* __restrict__ score){
  int p = blockIdx.x*256 + threadIdx.x;
  if (p >= N_EDGES) return;
  int e = perm[p];
  int s = src_perm[p];
  const float4* A = (const float4*)(aw + 128);
  float4 A0=A[0], A1=A[1], A2=A[2], A3=A[3];
  const float4* ev = (const float4*)(ef + (size_t)e*16);
  float4 v0=ev[0], v1=ev[1], v2=ev[2], v3=ev[3];
  float acc = s_src[s];
  acc += v0.x*A0.x + v0.y*A0.y + v0.z*A0.z + v0.w*A0.w;
  acc += v1.x*A1.x + v1.y*A1.y + v1.z*A1.z + v1.w*A1.w;
  acc += v2.x*A2.x + v2.y*A2.y + v2.z*A2.z + v2.w*A2.w;
  acc += v3.x*A3.x + v3.y*A3.y + v3.z*A3.z + v3.w*A3.w;
  score[p] = acc;
}

// ---------------------------------------------------------------------------
// GAT stage C: per-node softmax + alpha-weighted gather + leaky_relu
// ---------------------------------------------------------------------------
__global__ __launch_bounds__(256) void gat_aggregate(const int* __restrict__ row_start,
    const int* __restrict__ src_perm, const float* __restrict__ score,
    const float* __restrict__ ft, float* __restrict__ out){
  int lane = threadIdx.x & 63;
  int wv = threadIdx.x >> 6;
  int n = blockIdx.x*4 + wv;
  if (n >= N_NODES) return;
  int s = row_start[n], e = row_start[n+1];
  float m = -1e30f;
  for (int p = s+lane; p < e; p += 64) m = fmaxf(m, score[p]);
  #pragma unroll
  for (int off=32; off; off>>=1) m = fmaxf(m, __shfl_xor(m, off));
  float den = 0.f;
  for (int p = s+lane; p < e; p += 64) den += __expf(score[p]-m);
  #pragma unroll
  for (int off=32; off; off>>=1) den += __shfl_xor(den, off);
  float inv = (den > 0.f) ? 1.f/den : 0.f;
  float a0 = 0.f, a1 = 0.f;
  for (int p = s; p < e; p++){
    float al = __expf(score[p]-m)*inv;
    int sp = src_perm[p];
    float2 v = ((const float2*)(ft + (size_t)sp*128))[lane];
    a0 += al*v.x; a1 += al*v.y;
  }
  float2 o;
  o.x = (a0 > 0.f) ? a0 : 0.01f*a0;
  o.y = (a1 > 0.f) ? a1 : 0.01f*a1;
  ((float2*)(out + (size_t)n*128))[lane] = o;
}

// ---------------------------------------------------------------------------
extern "C" void kernel_launch(void* const* d_in, const int* in_sizes, int n_in,
                              void* d_out, int out_size, void* d_ws, size_t ws_size,
                              hipStream_t stream){
  (void)in_sizes; (void)n_in; (void)out_size; (void)ws_size;
  const int*   src     = (const int*)d_in[0] + (size_t)2*N_EDGES;       // j=2 slice
  const int*   dst     = (const int*)d_in[1] + (size_t)2*N_EDGES;
  const float* n_feats = (const float*)d_in[2] + (size_t)2*N_NODES*D;
  const float* e_feats = (const float*)d_in[3] + (size_t)2*N_EDGES*DE;
  const float* W0      = (const float*)d_in[4];
  const float* Wih     = (const float*)d_in[5];
  const float* Whh     = (const float*)d_in[6];
  const float* bih     = (const float*)d_in[7];
  const float* bhh     = (const float*)d_in[8];
  const float* a_w     = (const float*)d_in[9];
  float* out = (float*)d_out;

  char* wsp = (char*)d_ws;
  auto alloc = [&](size_t bytes)->char*{
    char* p = wsp; wsp += (bytes + 255) & ~(size_t)255; return p;
  };
  float* P         = (float*)alloc((size_t)2*128*512*4);
  float* xA        = (float*)alloc((size_t)2*128*128*4);
  float* xB        = (float*)alloc((size_t)2*128*128*4);
  int*   count     = (int*)  alloc((size_t)N_NODES*4);
  int*   bsum      = (int*)  alloc((size_t)NBLK*4);
  int*   boff      = (int*)  alloc((size_t)NBLK*4);
  int*   row_start = (int*)  alloc((size_t)(N_NODES+1)*4);
  int*   cursor    = (int*)  alloc((size_t)N_NODES*4);
  int*   perm      = (int*)  alloc((size_t)N_EDGES*4);
  int*   src_perm  = (int*)  alloc((size_t)N_EDGES*4);
  float* score     = (float*)alloc((size_t)N_EDGES*4);
  float* s_src     = (float*)alloc((size_t)N_NODES*4);
  float* ft        = (float*)alloc((size_t)N_NODES*D*4);
  float* f1        = (float*)alloc((size_t)N_NODES*D*4);

  // CSR build (once; same graph for both layers)
  hipMemsetAsync(count, 0, (size_t)N_NODES*4, stream);
  csr_hist     <<<(N_EDGES+255)/256, 256, 0, stream>>>(dst, count);
  csr_blocksum <<<NBLK, 256, 0, stream>>>(count, bsum);
  csr_scan_bsum<<<1,    256, 0, stream>>>(bsum, boff);
  csr_downsweep<<<NBLK, 256, 0, stream>>>(count, boff, row_start, cursor);
  csr_scatter  <<<(N_EDGES+255)/256, 256, 0, stream>>>(src, dst, cursor, perm, src_perm);

  // LSTM: 3 applications, both layers batched per launch; final W lands in xA
  const float* xi = W0;
  float* xo = xA;
  for (int app=0; app<3; app++){
    lstm_pre <<<256, 512, 0, stream>>>(Wih, bih, bhh, xi, P);
    lstm_scan<<<2,   256, 0, stream>>>(Whh, P, xo);
    xi = xo;
    xo = (app==0) ? xB : xA;
  }
  const float* Wfin = xA;   // app0->xA, app1->xB, app2->xA

  // Two GAT layers on graph j=2 (feats[0],feats[1] are dead w.r.t. output)
  const float* fin = n_feats;
  for (int l=0; l<2; l++){
    float* outl = (l==0) ? f1 : out;
    gat_transform <<<(N_NODES+31)/32, 256, 0, stream>>>(fin, Wfin + (size_t)l*16384,
                                                        a_w + (size_t)l*272, ft, s_src);
    gat_edge_score<<<(N_EDGES+255)/256, 256, 0, stream>>>(perm, src_perm, s_src,
                                                          e_feats, a_w + (size_t)l*272, score);
    gat_aggregate <<<N_NODES/4, 256, 0, stream>>>(row_start, src_perm, score, ft, outl);
    fin = f1;
  }
}

// Round 3
// 979.478 us; speedup vs baseline: 1.2209x; 1.2209x over previous
//
#include <hip/hip_runtime.h>
#include <cstdint>
#include <cstddef>

#define N_NODES 50000
#define N_EDGES 800000
#define D 128
#define DE 16
#define NBLK 196   // ceil(50000/256)

// ---------------------------------------------------------------------------
// CSR build (dst-sorted, graph j=2, shared by both layers)
// ---------------------------------------------------------------------------
__global__ void csr_hist(const int* __restrict__ dst, int* __restrict__ count){
  int e = blockIdx.x*256 + threadIdx.x;
  if (e < N_EDGES) atomicAdd(&count[dst[e]], 1);
}

__global__ __launch_bounds__(256) void csr_blocksum(const int* __restrict__ count,
                                                    int* __restrict__ bsum){
  __shared__ int red[4];
  int i = blockIdx.x*256 + threadIdx.x;
  int v = (i < N_NODES) ? count[i] : 0;
  #pragma unroll
  for (int off=32; off; off>>=1) v += __shfl_down(v, off);
  if ((threadIdx.x & 63) == 0) red[threadIdx.x>>6] = v;
  __syncthreads();
  if (threadIdx.x == 0) bsum[blockIdx.x] = red[0]+red[1]+red[2]+red[3];
}

__global__ __launch_bounds__(256) void csr_scan_bsum(const int* __restrict__ bsum,
                                                     int* __restrict__ boff){
  __shared__ int s[256];
  int t = threadIdx.x;
  int v = (t < NBLK) ? bsum[t] : 0;
  s[t] = v; __syncthreads();
  for (int off=1; off<256; off<<=1){
    int u = (t >= off) ? s[t-off] : 0;
    __syncthreads(); s[t] += u; __syncthreads();
  }
  if (t < NBLK) boff[t] = s[t] - v;   // exclusive
}

__global__ __launch_bounds__(256) void csr_downsweep(const int* __restrict__ count,
    const int* __restrict__ boff, int* __restrict__ row_start, int* __restrict__ cursor){
  __shared__ int s[256];
  int t = threadIdx.x;
  int i = blockIdx.x*256 + t;
  int v = (i < N_NODES) ? count[i] : 0;
  s[t] = v; __syncthreads();
  for (int off=1; off<256; off<<=1){
    int u = (t >= off) ? s[t-off] : 0;
    __syncthreads(); s[t] += u; __syncthreads();
  }
  int excl = boff[blockIdx.x] + s[t] - v;
  if (i <= N_NODES) row_start[i] = excl;
  if (i <  N_NODES) cursor[i]   = excl;
}

__global__ void csr_scatter(const int* __restrict__ src, const int* __restrict__ dst,
                            int* __restrict__ cursor, int* __restrict__ perm,
                            int* __restrict__ src_perm){
  int e = blockIdx.x*256 + threadIdx.x;
  if (e >= N_EDGES) return;
  int d = dst[e];
  int pos = atomicAdd(&cursor[d], 1);
  perm[pos] = e;
  src_perm[pos] = src[e];
}

// ---------------------------------------------------------------------------
// LSTM: P[t][r] = Wih[r] . x[t] + (bih[r]+bhh[r])   (wide, parallel)
// ---------------------------------------------------------------------------
__global__ __launch_bounds__(512) void lstm_pre(const float* __restrict__ Wih,
     const float* __restrict__ bih, const float* __restrict__ bhh,
     const float* __restrict__ xin, float* __restrict__ P){
  __shared__ float xs[128];
  int i = blockIdx.x >> 7, t = blockIdx.x & 127;
  const float* x = xin + (size_t)i*16384;
  if (threadIdx.x < 128) xs[threadIdx.x] = x[t*128 + threadIdx.x];
  __syncthreads();
  int r = threadIdx.x;
  const float4* wr = (const float4*)(Wih + (size_t)(i*512 + r)*128);
  const float4* x4 = (const float4*)xs;
  float acc = bih[i*512+r] + bhh[i*512+r];
  #pragma unroll
  for (int k=0;k<32;k++){
    float4 w = wr[k]; float4 xv = x4[k];
    acc += w.x*xv.x + w.y*xv.y + w.z*xv.z + w.w*xv.w;
  }
  P[(size_t)(i*128+t)*512 + r] = acc;
}

// Recurrent scan. 512 threads, 1 row/thread: 32 float4 weights = 128 VGPRs
// (arch VALU limit is 256 addressable VGPRs/wave — 2 rows/thread spills!).
// h broadcast via same-address ds_read_b128 (wave broadcast, conflict-free).
// 8 independent fp32 accumulator chains break the 4-cyc FMA dependency.
// rows: [0,128)=i  [128,256)=f  [256,384)=g(tanh)  [384,512)=o
// quarter boundaries align to wave boundaries -> nonlin branch is wave-uniform
__global__ __launch_bounds__(512, 2) void lstm_scan(const float* __restrict__ Whh,
     const float* __restrict__ P, float* __restrict__ xout){
  __shared__ float hs[128];
  __shared__ float gs[512];
  const int i = blockIdx.x, r = threadIdx.x;
  float4 w[32];
  {
    const float4* wr = (const float4*)(Whh + (size_t)(i*512 + r)*128);
    #pragma unroll
    for (int k=0;k<32;k++) w[k] = wr[k];
  }
  float c = 0.f;
  if (r < 128) hs[r] = 0.f;
  __syncthreads();
  const float* Pi = P + (size_t)i*128*512;
  for (int t=0;t<128;t++){
    float p = Pi[t*512 + r];                       // issue early; L2/L3-resident
    const float4* h4 = (const float4*)hs;
    float4 aA = make_float4(0.f,0.f,0.f,0.f);
    float4 aB = make_float4(0.f,0.f,0.f,0.f);
    #pragma unroll
    for (int k=0;k<32;k+=2){
      float4 ha = h4[k], hb = h4[k+1];
      float4 wa = w[k],  wb = w[k+1];
      aA.x += wa.x*ha.x; aA.y += wa.y*ha.y; aA.z += wa.z*ha.z; aA.w += wa.w*ha.w;
      aB.x += wb.x*hb.x; aB.y += wb.y*hb.y; aB.z += wb.z*hb.z; aB.w += wb.w*hb.w;
    }
    float acc = p + ((aA.x+aA.y) + (aA.z+aA.w)) + ((aB.x+aB.y) + (aB.z+aB.w));
    float g;
    if (r >= 256 && r < 384){                      // g gate: tanh (wave-uniform)
      float xc = fminf(fmaxf(acc, -15.f), 15.f);
      float e2 = __expf(2.f*xc);
      g = (e2 - 1.f) * __builtin_amdgcn_rcpf(e2 + 1.f);
    } else {                                       // i,f,o: sigmoid
      g = __builtin_amdgcn_rcpf(1.f + __expf(-acc));
    }
    gs[r] = g;
    __syncthreads();
    if (r < 128){
      c = gs[128+r]*c + gs[r]*gs[256+r];
      float xc = fminf(fmaxf(c, -15.f), 15.f);
      float e2 = __expf(2.f*xc);
      float th = (e2 - 1.f) * __builtin_amdgcn_rcpf(e2 + 1.f);
      float h = gs[384+r]*th;
      hs[r] = h;
      xout[(size_t)(i*128+t)*128 + r] = h;
    }
    __syncthreads();
  }
}

// ---------------------------------------------------------------------------
// GAT stage A: ft = f @ W (50000x128 @ 128x128, fp32) + s_src = f @ a_src
// ---------------------------------------------------------------------------
__global__ __launch_bounds__(256) void gat_transform(const float* __restrict__ f,
    const float* __restrict__ W, const float* __restrict__ aw,
    float* __restrict__ ft, float* __restrict__ s_src){
  __shared__ float Ws[64*128];
  __shared__ float fs[128*36];
  int n0 = blockIdx.x * 32;
  {
    int n = threadIdx.x >> 3, kq = threadIdx.x & 7;
    int gn = n0 + n;
    #pragma unroll
    for (int p=0;p<4;p++){
      int k = kq*16 + p*4;
      float4 v = make_float4(0.f,0.f,0.f,0.f);
      if (gn < N_NODES) v = *(const float4*)(f + (size_t)gn*128 + k);
      fs[(k+0)*36+n] = v.x; fs[(k+1)*36+n] = v.y;
      fs[(k+2)*36+n] = v.z; fs[(k+3)*36+n] = v.w;
    }
  }
  int jg = threadIdx.x & 31, ng = threadIdx.x >> 5;
  float4 a0=make_float4(0,0,0,0), a1=a0, a2=a0, a3=a0;
  for (int kk=0; kk<128; kk+=64){
    __syncthreads();
    {
      const float4* W4 = (const float4*)(W + (size_t)kk*128);
      float4* Ws4w = (float4*)Ws;
      for (int idx = threadIdx.x; idx < 2048; idx += 256) Ws4w[idx] = W4[idx];
    }
    __syncthreads();
    const float4* Ws4 = (const float4*)Ws;
    #pragma unroll 4
    for (int k2=0;k2<64;k2++){
      float4 wv = Ws4[k2*32 + jg];
      float4 fv = *(const float4*)&fs[(kk+k2)*36 + (ng<<2)];
      a0.x += fv.x*wv.x; a0.y += fv.x*wv.y; a0.z += fv.x*wv.z; a0.w += fv.x*wv.w;
      a1.x += fv.y*wv.x; a1.y += fv.y*wv.y; a1.z += fv.y*wv.z; a1.w += fv.y*wv.w;
      a2.x += fv.z*wv.x; a2.y += fv.z*wv.y; a2.z += fv.z*wv.z; a2.w += fv.z*wv.w;
      a3.x += fv.w*wv.x; a3.y += fv.w*wv.y; a3.z += fv.w*wv.z; a3.w += fv.w*wv.w;
    }
  }
  int nb = n0 + (ng<<2);
  if (nb+0 < N_NODES) *(float4*)(ft + (size_t)(nb+0)*128 + (jg<<2)) = a0;
  if (nb+1 < N_NODES) *(float4*)(ft + (size_t)(nb+1)*128 + (jg<<2)) = a1;
  if (nb+2 < N_NODES) *(float4*)(ft + (size_t)(nb+2)*128 + (jg<<2)) = a2;
  if (nb+3 < N_NODES) *(float4*)(ft + (size_t)(nb+3)*128 + (jg<<2)) = a3;
  if (threadIdx.x < 32){
    int gn = n0 + threadIdx.x;
    if (gn < N_NODES){
      float s = 0.f;
      for (int k=0;k<128;k++) s += fs[k*36 + threadIdx.x] * aw[k];
      s_src[gn] = s;
    }
  }
}

// ---------------------------------------------------------------------------
// GAT stage B: score[p] = s_src[src_perm[p]] + ef[perm[p]] . a_edge
// ---------------------------------------------------------------------------
__global__ __launch_bounds__(256) void gat_edge_score(const int* __restrict__ perm,
    const int* __restrict__ src_perm, const float* __restrict__ s_src,
    const float* __restrict__ ef, const float* __restrict__ aw,
    float* __restrict__ score){
  int p = blockIdx.x*256 + threadIdx.x;
  if (p >= N_EDGES) return;
  int e = perm[p];
  int s = src_perm[p];
  const float4* A = (const float4*)(aw + 128);
  float4 A0=A[0], A1=A[1], A2=A[2], A3=A[3];
  const float4* ev = (const float4*)(ef + (size_t)e*16);
  float4 v0=ev[0], v1=ev[1], v2=ev[2], v3=ev[3];
  float acc = s_src[s];
  acc += v0.x*A0.x + v0.y*A0.y + v0.z*A0.z + v0.w*A0.w;
  acc += v1.x*A1.x + v1.y*A1.y + v1.z*A1.z + v1.w*A1.w;
  acc += v2.x*A2.x + v2.y*A2.y + v2.z*A2.z + v2.w*A2.w;
  acc += v3.x*A3.x + v3.y*A3.y + v3.z*A3.z + v3.w*A3.w;
  score[p] = acc;
}

// ---------------------------------------------------------------------------
// GAT stage C: per-node softmax + alpha-weighted gather + leaky_relu
// ---------------------------------------------------------------------------
__global__ __launch_bounds__(256) void gat_aggregate(const int* __restrict__ row_start,
    const int* __restrict__ src_perm, const float* __restrict__ score,
    const float* __restrict__ ft, float* __restrict__ out){
  int lane = threadIdx.x & 63;
  int wv = threadIdx.x >> 6;
  int n = blockIdx.x*4 + wv;
  if (n >= N_NODES) return;
  int s = row_start[n], e = row_start[n+1];
  float m = -1e30f;
  for (int p = s+lane; p < e; p += 64) m = fmaxf(m, score[p]);
  #pragma unroll
  for (int off=32; off; off>>=1) m = fmaxf(m, __shfl_xor(m, off));
  float den = 0.f;
  for (int p = s+lane; p < e; p += 64) den += __expf(score[p]-m);
  #pragma unroll
  for (int off=32; off; off>>=1) den += __shfl_xor(den, off);
  float inv = (den > 0.f) ? 1.f/den : 0.f;
  float a0 = 0.f, a1 = 0.f;
  for (int p = s; p < e; p++){
    float al = __expf(score[p]-m)*inv;
    int sp = src_perm[p];
    float2 v = ((const float2*)(ft + (size_t)sp*128))[lane];
    a0 += al*v.x; a1 += al*v.y;
  }
  float2 o;
  o.x = (a0 > 0.f) ? a0 : 0.01f*a0;
  o.y = (a1 > 0.f) ? a1 : 0.01f*a1;
  ((float2*)(out + (size_t)n*128))[lane] = o;
}

// ---------------------------------------------------------------------------
extern "C" void kernel_launch(void* const* d_in, const int* in_sizes, int n_in,
                              void* d_out, int out_size, void* d_ws, size_t ws_size,
                              hipStream_t stream){
  (void)in_sizes; (void)n_in; (void)out_size; (void)ws_size;
  const int*   src     = (const int*)d_in[0] + (size_t)2*N_EDGES;       // j=2 slice
  const int*   dst     = (const int*)d_in[1] + (size_t)2*N_EDGES;
  const float* n_feats = (const float*)d_in[2] + (size_t)2*N_NODES*D;
  const float* e_feats = (const float*)d_in[3] + (size_t)2*N_EDGES*DE;
  const float* W0      = (const float*)d_in[4];
  const float* Wih     = (const float*)d_in[5];
  const float* Whh     = (const float*)d_in[6];
  const float* bih     = (const float*)d_in[7];
  const float* bhh     = (const float*)d_in[8];
  const float* a_w     = (const float*)d_in[9];
  float* out = (float*)d_out;

  char* wsp = (char*)d_ws;
  auto alloc = [&](size_t bytes)->char*{
    char* p = wsp; wsp += (bytes + 255) & ~(size_t)255; return p;
  };
  float* P         = (float*)alloc((size_t)2*128*512*4);
  float* xA        = (float*)alloc((size_t)2*128*128*4);
  float* xB        = (float*)alloc((size_t)2*128*128*4);
  int*   count     = (int*)  alloc((size_t)N_NODES*4);
  int*   bsum      = (int*)  alloc((size_t)NBLK*4);
  int*   boff      = (int*)  alloc((size_t)NBLK*4);
  int*   row_start = (int*)  alloc((size_t)(N_NODES+1)*4);
  int*   cursor    = (int*)  alloc((size_t)N_NODES*4);
  int*   perm      = (int*)  alloc((size_t)N_EDGES*4);
  int*   src_perm  = (int*)  alloc((size_t)N_EDGES*4);
  float* score     = (float*)alloc((size_t)N_EDGES*4);
  float* s_src     = (float*)alloc((size_t)N_NODES*4);
  float* ft        = (float*)alloc((size_t)N_NODES*D*4);
  float* f1        = (float*)alloc((size_t)N_NODES*D*4);

  // CSR build (once; same graph for both layers)
  hipMemsetAsync(count, 0, (size_t)N_NODES*4, stream);
  csr_hist     <<<(N_EDGES+255)/256, 256, 0, stream>>>(dst, count);
  csr_blocksum <<<NBLK, 256, 0, stream>>>(count, bsum);
  csr_scan_bsum<<<1,    256, 0, stream>>>(bsum, boff);
  csr_downsweep<<<NBLK, 256, 0, stream>>>(count, boff, row_start, cursor);
  csr_scatter  <<<(N_EDGES+255)/256, 256, 0, stream>>>(src, dst, cursor, perm, src_perm);

  // LSTM: 3 applications, both layers batched per launch; final W lands in xA
  const float* xi = W0;
  float* xo = xA;
  for (int app=0; app<3; app++){
    lstm_pre <<<256, 512, 0, stream>>>(Wih, bih, bhh, xi, P);
    lstm_scan<<<2,   512, 0, stream>>>(Whh, P, xo);
    xi = xo;
    xo = (app==0) ? xB : xA;
  }
  const float* Wfin = xA;   // app0->xA, app1->xB, app2->xA

  // Two GAT layers on graph j=2 (feats[0],feats[1] are dead w.r.t. output)
  const float* fin = n_feats;
  for (int l=0; l<2; l++){
    float* outl = (l==0) ? f1 : out;
    gat_transform <<<(N_NODES+31)/32, 256, 0, stream>>>(fin, Wfin + (size_t)l*16384,
                                                        a_w + (size_t)l*272, ft, s_src);
    gat_edge_score<<<(N_EDGES+255)/256, 256, 0, stream>>>(perm, src_perm, s_src,
                                                          e_feats, a_w + (size_t)l*272, score);
    gat_aggregate <<<N_NODES/4, 256, 0, stream>>>(row_start, src_perm, score, ft, outl);
    fin = f1;
  }
}